// Round 1
// baseline (90.153 us; speedup 1.0000x reference)
//
#include <hip/hip_runtime.h>
#include <math.h>

// PeakSense: out[b,p] = sum_i exp(-0.5*(mz[b,i]-mu[p])^2 * exp(-lv[p])) * iv[b,i]
// with terms dropped when arg < -10.
//
// Exploits: (1) masses sorted per row -> chunk [min,max] window known from
// first/last LDS element; (2) threshold -> peak p only sees masses within
// r = sqrt(20)*sigma_p (~7.9 mass units here) -> whole waves skip chunks.
// SUB=4 threads per peak so one wave spans only 16 consecutive peaks,
// tightening the wave-skip window.

#define CHUNK 512
#define SUB 4
#define BLOCK 256
#define PEAKS_PER_BLOCK (BLOCK / SUB)   // 64
#define THRESH -10.0f

__global__ __launch_bounds__(BLOCK) void peaksense_kernel(
    const float* __restrict__ mu,
    const float* __restrict__ lv,
    const float* __restrict__ masses,
    const float* __restrict__ inten,
    float* __restrict__ out,
    int B, int L, int N, int nchunks, int pgroups)
{
    __shared__ float s_m[CHUNK];
    __shared__ float s_iv[CHUNK];

    const int bid = blockIdx.x;
    const int pg  = bid % pgroups;
    const int c   = (bid / pgroups) % nchunks;
    const int b   = bid / (pgroups * nchunks);

    const int t = threadIdx.x;
    int n = L - c * CHUNK;
    if (n > CHUNK) n = CHUNK;

    const float* __restrict__ mrow = masses + (size_t)b * L + (size_t)c * CHUNK;
    const float* __restrict__ irow = inten  + (size_t)b * L + (size_t)c * CHUNK;
    for (int i = t; i < n; i += BLOCK) {
        s_m[i]  = mrow[i];
        s_iv[i] = irow[i];
    }
    __syncthreads();

    const int lp  = t >> 2;           // local peak 0..63
    const int sub = t & (SUB - 1);    // 0..3: which quarter of the chunk
    const int p   = pg * PEAKS_PER_BLOCK + lp;
    const bool valid = (p < N);

    const float mu_p  = valid ? mu[p] : 0.0f;
    const float inv   = valid ? __expf(-lv[p]) : 1.0f;  // 1/sigma^2
    const float nhinv = -0.5f * inv;
    // arg >= -10  <=>  d^2 <= 20/inv  <=>  |d| <= r  (tiny margin for rounding)
    const float r = sqrtf(20.0f / inv) * 1.000002f;

    const float cmin = s_m[0];
    const float cmax = s_m[n - 1];    // sorted chunk -> window is [cmin, cmax]

    bool active = valid && (mu_p >= cmin - r) && (mu_p <= cmax + r);
    if (__ballot(active) == 0ull) return;   // whole wave out of this chunk's window

    float acc = 0.0f;
    if (active) {
        for (int i = sub; i < n; i += SUB) {
            float d   = s_m[i] - mu_p;       // LDS reads: 4 distinct addrs/wave, no conflict
            float arg = d * d * nhinv;
            if (arg >= THRESH)
                acc += __expf(arg) * s_iv[i];
        }
    }
    // combine the 4 sub-lanes that share a peak (lanes 4k..4k+3)
    acc += __shfl_xor(acc, 1);
    acc += __shfl_xor(acc, 2);
    if (sub == 0 && acc != 0.0f)
        atomicAdd(&out[(size_t)b * N + p], acc);
}

extern "C" void kernel_launch(void* const* d_in, const int* in_sizes, int n_in,
                              void* d_out, int out_size, void* d_ws, size_t ws_size,
                              hipStream_t stream) {
    const float* mu     = (const float*)d_in[0];
    const float* lv     = (const float*)d_in[1];
    const float* masses = (const float*)d_in[2];
    const float* inten  = (const float*)d_in[3];
    float* out = (float*)d_out;

    const int N  = in_sizes[0];
    const int B  = out_size / N;
    const int L  = in_sizes[2] / B;
    const int nchunks = (L + CHUNK - 1) / CHUNK;
    const int pgroups = (N + PEAKS_PER_BLOCK - 1) / PEAKS_PER_BLOCK;

    // harness poisons d_out with 0xAA; we accumulate with atomics -> zero it first
    hipMemsetAsync(d_out, 0, (size_t)out_size * sizeof(float), stream);

    dim3 grid(B * nchunks * pgroups);
    peaksense_kernel<<<grid, BLOCK, 0, stream>>>(mu, lv, masses, inten, out,
                                                 B, L, N, nchunks, pgroups);
}

// Round 2
// 70.475 us; speedup vs baseline: 1.2792x; 1.2792x over previous
//
#include <hip/hip_runtime.h>
#include <math.h>

// PeakSense: out[b,p] = sum_i exp(-0.5*(mz[b,i]-mu[p])^2 * exp(-lv[p])) * iv[b,i],
// terms with arg < -10 dropped.
//
// Mapping: one wave = 64 consecutive sorted masses (register-resident, no LDS).
// Wave span known from lanes 0/63. Candidate peaks (those whose +/-r window
// overlaps the span, r = sqrt(20)*sigma) found via 4 coalesced predicated
// passes + ballot (~9 candidates/wave). Inner loop broadcasts peak params via
// shfl from the lane that loaded them; 64 terms/peak in parallel; 6-step
// shfl_xor reduce; one atomicAdd per (wave,peak). True sparse work ~2.3M
// exp-terms; this does ~4.7M lane-terms (~50% efficiency) vs 28M in round 1.

#define BLOCK 256
#define THRESH -10.0f

__global__ __launch_bounds__(BLOCK) void peaksense_kernel(
    const float* __restrict__ mu,
    const float* __restrict__ lv,
    const float* __restrict__ masses,
    const float* __restrict__ inten,
    float* __restrict__ out,
    int B, int L, int N)
{
    const int b    = blockIdx.y;
    const int i0   = blockIdx.x * BLOCK + threadIdx.x;
    const int lane = threadIdx.x & 63;
    const int wbase = blockIdx.x * BLOCK + (threadIdx.x & ~63); // first mass idx of this wave
    int nv = L - wbase;
    if (nv <= 0) return;          // whole wave past the row end (no LDS/sync in kernel)
    if (nv > 64) nv = 64;

    const size_t rowoff = (size_t)b * L;
    const bool vload = (i0 < L);
    // Invalid lanes: m=+inf -> arg=-inf -> predicate false; iv=0 belt-and-braces.
    const float m  = vload ? masses[rowoff + i0] : INFINITY;
    const float iv = vload ? inten[rowoff + i0] : 0.0f;

    const float m_lo = __shfl(m, 0);        // masses sorted per row
    const float m_hi = __shfl(m, nv - 1);

    float* __restrict__ outrow = out + (size_t)b * N;

    const int nk = (N + 63) / 64;
    for (int k = 0; k < nk; ++k) {
        const int pc = k * 64 + lane;
        float mu_l = 0.0f, nh_l = 0.0f;
        bool cand = false;
        if (pc < N) {
            mu_l = mu[pc];                         // coalesced, L2/L3-resident
            const float lvl = lv[pc];
            nh_l = -0.5f * __expf(-lvl);           // -0.5/sigma^2
            // arg >= -10  <=>  |d| <= sqrt(20)*sigma ; margin for fp rounding.
            const float r = sqrtf(20.0f * __expf(lvl)) * 1.00001f + 1e-3f;
            cand = (mu_l + r >= m_lo) && (mu_l - r <= m_hi);
        }
        unsigned long long mask = __ballot(cand);
        while (mask) {
            const int s = (int)__builtin_ctzll(mask);  // wave-uniform candidate lane
            mask &= mask - 1;
            const float mu_p = __shfl(mu_l, s);
            const float nh_p = __shfl(nh_l, s);
            const float d    = m - mu_p;
            const float arg  = d * d * nh_p;
            float t = (arg >= THRESH) ? __expf(arg) * iv : 0.0f;
            // wave-wide sum (64 lanes)
            t += __shfl_xor(t, 1);
            t += __shfl_xor(t, 2);
            t += __shfl_xor(t, 4);
            t += __shfl_xor(t, 8);
            t += __shfl_xor(t, 16);
            t += __shfl_xor(t, 32);
            if (lane == 0)
                atomicAdd(&outrow[k * 64 + s], t);   // ~2 waves touch each (b,p)
        }
    }
}

extern "C" void kernel_launch(void* const* d_in, const int* in_sizes, int n_in,
                              void* d_out, int out_size, void* d_ws, size_t ws_size,
                              hipStream_t stream) {
    const float* mu     = (const float*)d_in[0];
    const float* lv     = (const float*)d_in[1];
    const float* masses = (const float*)d_in[2];
    const float* inten  = (const float*)d_in[3];
    float* out = (float*)d_out;

    const int N = in_sizes[0];
    const int B = out_size / N;
    const int L = in_sizes[2] / B;

    // harness poisons d_out with 0xAA; we accumulate with atomics -> zero first
    hipMemsetAsync(d_out, 0, (size_t)out_size * sizeof(float), stream);

    dim3 grid((L + BLOCK - 1) / BLOCK, B);
    peaksense_kernel<<<grid, BLOCK, 0, stream>>>(mu, lv, masses, inten, out, B, L, N);
}

// Round 3
// 70.217 us; speedup vs baseline: 1.2839x; 1.0037x over previous
//
#include <hip/hip_runtime.h>
#include <math.h>

// PeakSense: out[b,p] = sum_i exp(-0.5*(mz[b,i]-mu[p])^2 * exp(-lv[p])) * iv[b,i],
// terms with arg < -10 dropped.
//
// One thread owns one (b,p) half-range: block = 128 peaks x 2 subs, block
// stages its whole sorted mass row as float2{m,iv} in 32KB LDS, each thread
// binary-searches the +/-r window (r = sqrt(20)*sigma, the exact threshold
// radius) and sums its ~36 terms in-register. shfl_xor(1) merges the sub
// pair; each output written exactly once with '=' -> no memset, no atomics,
// single dispatch. Sparse work ~2.3M exp-terms vs 134M dense.

#define BLOCK 256
#define SUB 2
#define PPB (BLOCK / SUB)   // 128 peaks per block
#define MAXL 4096
#define THRESH -10.0f

__global__ __launch_bounds__(BLOCK) void peaksense_kernel(
    const float* __restrict__ mu,
    const float* __restrict__ lv,
    const float* __restrict__ masses,
    const float* __restrict__ inten,
    float* __restrict__ out,
    int B, int L, int N)
{
    __shared__ float2 s[MAXL];   // interleaved {mass, intensity}, 32 KB

    const int pg = blockIdx.x;   // peak group
    const int b  = blockIdx.y;
    const int t  = threadIdx.x;

    // stage the whole row (coalesced; L <= MAXL)
    const float* __restrict__ mrow = masses + (size_t)b * L;
    const float* __restrict__ irow = inten  + (size_t)b * L;
    for (int i = t; i < L; i += BLOCK)
        s[i] = make_float2(mrow[i], irow[i]);
    __syncthreads();

    const int lp  = t >> 1;        // local peak 0..127
    const int sub = t & 1;         // half-range selector
    const int p   = pg * PPB + lp;
    if (p >= N) return;            // no further barriers below

    const float mu_p = mu[p];                  // lanes 2k,2k+1 broadcast-share
    const float lvp  = lv[p];
    const float inv  = __expf(-lvp);           // 1/sigma^2
    const float nh   = -0.5f * inv;
    // arg >= -10  <=>  |d| <= sqrt(20)*sigma; margin covers fp rounding, the
    // exact per-term test below keeps the result bit-for-bit safe.
    const float r    = sqrtf(20.0f / inv) * 1.00001f + 1e-3f;
    const float tlo  = mu_p - r;
    const float thi  = mu_p + r;

    // lower bound: first i with m >= tlo
    int lo = 0, hi = L;
    while (lo < hi) {
        int mid = (lo + hi) >> 1;
        if (s[mid].x < tlo) lo = mid + 1; else hi = mid;
    }
    const int start = lo;
    // exclusive end: first i with m > thi
    int lo2 = start, hi2 = L;
    while (lo2 < hi2) {
        int mid = (lo2 + hi2) >> 1;
        if (s[mid].x <= thi) lo2 = mid + 1; else hi2 = mid;
    }
    const int end = lo2;

    float acc = 0.0f;
    for (int i = start + sub; i < end; i += SUB) {
        const float2 v = s[i];                 // ds_read_b64
        const float d   = v.x - mu_p;
        const float arg = d * d * nh;
        if (arg >= THRESH)
            acc += __expf(arg) * v.y;
    }
    acc += __shfl_xor(acc, 1);                 // merge sub pair (same wave)
    if (sub == 0)
        out[(size_t)b * N + p] = acc;          // exactly-once '=' write
}

extern "C" void kernel_launch(void* const* d_in, const int* in_sizes, int n_in,
                              void* d_out, int out_size, void* d_ws, size_t ws_size,
                              hipStream_t stream) {
    const float* mu     = (const float*)d_in[0];
    const float* lv     = (const float*)d_in[1];
    const float* masses = (const float*)d_in[2];
    const float* inten  = (const float*)d_in[3];
    float* out = (float*)d_out;

    const int N = in_sizes[0];
    const int B = out_size / N;
    const int L = in_sizes[2] / B;

    const int pgroups = (N + PPB - 1) / PPB;   // 2 for N=256
    dim3 grid(pgroups, B);                     // 256 blocks -> one per CU
    peaksense_kernel<<<grid, BLOCK, 0, stream>>>(mu, lv, masses, inten, out, B, L, N);
}